// Round 1
// baseline (336.311 us; speedup 1.0000x reference)
//
#include <hip/hip_runtime.h>
#include <hip/hip_bf16.h>

// InfoNCE: a[4096,512], p[4096,512], n[16384,512] f32 -> 4 f32 scalars.
// R5: whole-K-resident GEMM. K=512 at fp8 means a full 128-row panel is 64KB,
//     so A-panel + B-panel (128KB) both fit in LDS at once. The K-loop (and its
//     8 barriers + vmcnt(0) drains per block, the R4 bottleneck: MfmaUtil 25%,
//     >50% all-stall) collapses to: stage once -> ONE barrier -> 256 MFMAs.
//     512 thr / 8 waves (2 per SIMD), wave grid 4(M)x2(N), 32x64 out per wave.
//     XOR-swizzle + K-permutation (g = t*4+q, same for A and B) kept from R4,
//     widened to 32 granules/row: per-quad phase pattern unchanged -> 0 bank
//     conflicts on ds_read_b128.
// ws layout: a8(2MB) p8(2MB) n8(8MB) | S[4096] csA[512*16] csP[512*16] csN[512*16] lsum[1]

#define D_DIM 512
#define B_ROWS 4096
#define P_ROWS 4096
#define N_ROWS 16384
#define INV_T 14.285714285714286f
#define EPS_L 1e-8f
#define CS_STRIDE 16  // colsum accumulators spread 64B apart -> atomics hit distinct lines

typedef unsigned char fp8_t;
typedef __attribute__((ext_vector_type(4))) float floatx4;   // MFMA C/D frag
typedef __attribute__((ext_vector_type(2))) long longx2;     // 16B LDS read = 2 MFMA operands
typedef unsigned int uint32;

// ---- fused: L2-normalize rows -> fp8 e4m3, and accumulate fp32 column sums ----
// grid = 1024 blocks x 256 thr. Segments: b<256 -> A, b<512 -> P, else -> N.
__global__ __launch_bounds__(256) void norm_colsum(
        const float* __restrict__ a, const float* __restrict__ p, const float* __restrict__ n,
        fp8_t* __restrict__ a8, fp8_t* __restrict__ p8, fp8_t* __restrict__ n8,
        float* __restrict__ csA, float* __restrict__ csP, float* __restrict__ csN) {
    const float* in; fp8_t* outp; float* cs; int rows, nb, bseg;
    int b = blockIdx.x;
    if (b < 256)      { in = a; outp = a8; cs = csA; rows = B_ROWS; nb = 256; bseg = b; }
    else if (b < 512) { in = p; outp = p8; cs = csP; rows = P_ROWS; nb = 256; bseg = b - 256; }
    else              { in = n; outp = n8; cs = csN; rows = N_ROWS; nb = 512; bseg = b - 512; }

    const int wave = threadIdx.x >> 6;
    const int lane = threadIdx.x & 63;

    float cs0[4] = {0.f, 0.f, 0.f, 0.f};
    float cs1[4] = {0.f, 0.f, 0.f, 0.f};

    for (int chunk = bseg; chunk < (rows >> 2); chunk += nb) {
        int r = chunk * 4 + wave;
        const float4* rp = reinterpret_cast<const float4*>(in + (size_t)r * D_DIM);
        float4 v0 = rp[lane];
        float4 v1 = rp[lane + 64];
        float ss = v0.x*v0.x + v0.y*v0.y + v0.z*v0.z + v0.w*v0.w
                 + v1.x*v1.x + v1.y*v1.y + v1.z*v1.z + v1.w*v1.w;
#pragma unroll
        for (int off = 1; off < 64; off <<= 1) ss += __shfl_xor(ss, off);
        float inv = 1.0f / fmaxf(sqrtf(ss), 1e-12f);
        float f0x = v0.x*inv, f0y = v0.y*inv, f0z = v0.z*inv, f0w = v0.w*inv;
        float f1x = v1.x*inv, f1y = v1.y*inv, f1z = v1.z*inv, f1w = v1.w*inv;
        cs0[0] += f0x; cs0[1] += f0y; cs0[2] += f0z; cs0[3] += f0w;
        cs1[0] += f1x; cs1[1] += f1y; cs1[2] += f1z; cs1[3] += f1w;
        // pack 4 floats -> 4 fp8 e4m3 bytes (RNE hw cvt)
        int pk0 = __builtin_amdgcn_cvt_pk_fp8_f32(f0x, f0y, 0, 0);
        pk0     = __builtin_amdgcn_cvt_pk_fp8_f32(f0z, f0w, pk0, 1);
        int pk1 = __builtin_amdgcn_cvt_pk_fp8_f32(f1x, f1y, 0, 0);
        pk1     = __builtin_amdgcn_cvt_pk_fp8_f32(f1z, f1w, pk1, 1);
        uint32* op = reinterpret_cast<uint32*>(outp + (size_t)r * D_DIM);
        op[lane]      = (uint32)pk0;   // bytes 4*lane .. 4*lane+3
        op[lane + 64] = (uint32)pk1;   // bytes 256+4*lane ..
    }

    // block-level colsum reduce: LDS atomics (4-way max contention), then one
    // global atomic per column per block, spread across 64B lines.
    __shared__ float csh[D_DIM];
    if (threadIdx.x < 256) { csh[threadIdx.x] = 0.f; csh[threadIdx.x + 256] = 0.f; }
    __syncthreads();
#pragma unroll
    for (int j = 0; j < 4; ++j) {
        atomicAdd(&csh[lane * 4 + j], cs0[j]);
        atomicAdd(&csh[256 + lane * 4 + j], cs1[j]);
    }
    __syncthreads();
    if (threadIdx.x < 256) {
        atomicAdd(&cs[(size_t)threadIdx.x * CS_STRIDE], csh[threadIdx.x]);
        atomicAdd(&cs[(size_t)(threadIdx.x + 256) * CS_STRIDE], csh[threadIdx.x + 256]);
    }
}

// ---------------- fp8 MFMA GEMM, whole-K resident, fused epilogue ----------------
#define BM 128
#define BN 128

typedef const __attribute__((address_space(1))) unsigned int* as1_u32p;
typedef __attribute__((address_space(3))) unsigned int* as3_u32p;

__device__ __forceinline__ void load_lds16(const void* g, void* l) {
    // each lane writes 16B at (wave-uniform l) + lane*16
    __builtin_amdgcn_global_load_lds((as1_u32p)g, (as3_u32p)l, 16, 0, 0);
}

// EPI==0: C = A@Bm^T, S[row] += sum_col exp(C*invT)           (neg pass)
// EPI==1: loss_sum += sum(-log(exp(C*invT)/(exp+S[row])+eps)) (pos pass)
template <int EPI>
__global__ __launch_bounds__(512, 2) void gemm_epi(const fp8_t* __restrict__ A,
                                                   const fp8_t* __restrict__ Bm,
                                                   float* __restrict__ S,
                                                   float* __restrict__ loss_sum) {
    __shared__ fp8_t As[BM * D_DIM];  // 64 KB: full A panel, all of K
    __shared__ fp8_t Bs[BN * D_DIM];  // 64 KB: full B panel, all of K

    const int tid  = threadIdx.x;
    const int lane = tid & 63;
    const int w    = tid >> 6;          // wave 0..7
    const int wm   = w >> 1;            // 0..3: M quarter (32 rows)
    const int wn   = w & 1;             // 0..1: N half    (64 cols)
    const int m0   = blockIdx.y * BM;
    const int n0   = blockIdx.x * BN;
    const int lr   = lane & 15;         // row-in-16-tile for frags
    const int q    = lane >> 4;         // quad 0..3

    // ---- stage both whole-K panels (one burst, one barrier) ----
    // wave w stages rows [w*16, w*16+16) of A and B; each call covers 2 rows
    // (64 lanes x 16B = 1KB). LDS[r*512 + s*16] holds global granule s^(r&7)
    // of row r (XOR swizzle folded into the per-lane gather address;
    // global_load_lds LDS dest is lane-contiguous and wave-uniform-based).
    {
        const int rl = lane >> 5;        // row within the 2-row call
        const int s  = lane & 31;        // LDS granule slot 0..31
#pragma unroll
        for (int i = 0; i < 8; ++i) {
            int r0 = w * 16 + i * 2;     // wave-uniform, even
            int r  = r0 + rl;
            int g  = s ^ (r & 7);        // swizzled source granule
            load_lds16(A  + (size_t)(m0 + r) * D_DIM + g * 16, &As[r0 * D_DIM]);
            load_lds16(Bm + (size_t)(n0 + r) * D_DIM + g * 16, &Bs[r0 * D_DIM]);
        }
    }

    floatx4 acc[2][4];
#pragma unroll
    for (int i = 0; i < 2; ++i)
#pragma unroll
        for (int j = 0; j < 4; ++j) acc[i][j] = (floatx4){0.f, 0.f, 0.f, 0.f};

    __syncthreads();  // single drain: compiler emits vmcnt(0) before s_barrier

    // ---- 16 MFMA k-steps, zero intermediate barriers ----
    // K-permuted fragment reads: lane reads granule g = t*4+q (b128, per-quad
    // phase pattern is conflict-free), halves feed MFMA calls 2t and 2t+1.
    // Same (t,q,h)->k mapping for A and B => dot product is exact.
#pragma unroll
    for (int t = 0; t < 8; ++t) {
        longx2 af[2], bfr[4];
        const int g = t * 4 + q;
#pragma unroll
        for (int rt = 0; rt < 2; ++rt) {
            int r = wm * 32 + rt * 16 + lr;
            int off = (g ^ (r & 7)) << 4;
            af[rt] = *reinterpret_cast<const longx2*>(&As[r * D_DIM + off]);
        }
#pragma unroll
        for (int ct = 0; ct < 4; ++ct) {
            int r = wn * 64 + ct * 16 + lr;
            int off = (g ^ (r & 7)) << 4;
            bfr[ct] = *reinterpret_cast<const longx2*>(&Bs[r * D_DIM + off]);
        }
#pragma unroll
        for (int rt = 0; rt < 2; ++rt)
#pragma unroll
            for (int ct = 0; ct < 4; ++ct)
                acc[rt][ct] = __builtin_amdgcn_mfma_f32_16x16x32_fp8_fp8(af[rt].x, bfr[ct].x,
                                                                         acc[rt][ct], 0, 0, 0);
#pragma unroll
        for (int rt = 0; rt < 2; ++rt)
#pragma unroll
            for (int ct = 0; ct < 4; ++ct)
                acc[rt][ct] = __builtin_amdgcn_mfma_f32_16x16x32_fp8_fp8(af[rt].y, bfr[ct].y,
                                                                         acc[rt][ct], 0, 0, 0);
    }

    // C/D layout: col = lane&15, row = (lane>>4)*4 + reg
    if (EPI == 0) {
        // per row: sum exp over this wave's 64 columns, then one atomic per
        // (row, wn) -> 2 global atomics per row per block (same as R4).
#pragma unroll
        for (int rt = 0; rt < 2; ++rt) {
#pragma unroll
            for (int reg = 0; reg < 4; ++reg) {
                float v = 0.f;
#pragma unroll
                for (int ct = 0; ct < 4; ++ct) v += __expf(acc[rt][ct][reg] * INV_T);
                v += __shfl_xor(v, 1);
                v += __shfl_xor(v, 2);
                v += __shfl_xor(v, 4);
                v += __shfl_xor(v, 8);
                if (lr == 0) {
                    int row = m0 + wm * 32 + rt * 16 + q * 4 + reg;
                    atomicAdd(&S[row], v);
                }
            }
        }
    } else {
        float lsum = 0.f;
#pragma unroll
        for (int rt = 0; rt < 2; ++rt) {
#pragma unroll
            for (int reg = 0; reg < 4; ++reg) {
                int row = m0 + wm * 32 + rt * 16 + q * 4 + reg;
                float Sv = S[row];
#pragma unroll
                for (int ct = 0; ct < 4; ++ct) {
                    float pe = __expf(acc[rt][ct][reg] * INV_T);
                    lsum -= __logf(pe / (pe + Sv) + EPS_L);
                }
            }
        }
#pragma unroll
        for (int off = 1; off < 64; off <<= 1) lsum += __shfl_xor(lsum, off);
        // 8 waves -> 1 global atomic per block: reuse As as scratch (all LDS
        // reads are complete past this barrier).
        __syncthreads();
        float* red = reinterpret_cast<float*>(As);
        if (lane == 0) red[w] = lsum;
        __syncthreads();
        if (tid == 0) {
            float s = 0.f;
#pragma unroll
            for (int i = 0; i < 8; ++i) s += red[i];
            atomicAdd(loss_sum, s);
        }
    }
}

// ---- finalize: dot the (strided) column sums, emit the 4 scalars ----
__global__ void finalize_k(const float* __restrict__ csA, const float* __restrict__ csP,
                           const float* __restrict__ csN, const float* __restrict__ lsum,
                           float* __restrict__ out) {
    int tid = threadIdx.x;  // 512
    float av = csA[(size_t)tid * CS_STRIDE];
    float dp = av * csP[(size_t)tid * CS_STRIDE];
    float dn = av * csN[(size_t)tid * CS_STRIDE];
#pragma unroll
    for (int off = 1; off < 64; off <<= 1) {
        dp += __shfl_xor(dp, off);
        dn += __shfl_xor(dn, off);
    }
    __shared__ float red[16];
    int wid = tid >> 6, lane = tid & 63;
    if (lane == 0) { red[wid] = dp; red[8 + wid] = dn; }
    __syncthreads();
    if (tid == 0) {
        float sdp = 0.f, sdn = 0.f;
#pragma unroll
        for (int i = 0; i < 8; ++i) { sdp += red[i]; sdn += red[8 + i]; }
        float mean_pos = sdp * INV_T / ((float)B_ROWS * (float)P_ROWS);
        float mean_neg = sdn * INV_T / ((float)B_ROWS * (float)N_ROWS);
        out[0] = lsum[0] / ((float)B_ROWS * (float)P_ROWS);
        out[1] = mean_pos;
        out[2] = mean_neg;
        out[3] = mean_pos - mean_neg;
    }
}

extern "C" void kernel_launch(void* const* d_in, const int* in_sizes, int n_in,
                              void* d_out, int out_size, void* d_ws, size_t ws_size,
                              hipStream_t stream) {
    const float* anc = (const float*)d_in[0];
    const float* pos = (const float*)d_in[1];
    const float* neg = (const float*)d_in[2];
    float* out = (float*)d_out;

    fp8_t* a8 = (fp8_t*)d_ws;
    fp8_t* p8 = a8 + (size_t)B_ROWS * D_DIM;
    fp8_t* n8 = p8 + (size_t)P_ROWS * D_DIM;
    float* fsec = (float*)(n8 + (size_t)N_ROWS * D_DIM);  // 12MB offset, 64B-aligned
    float* S    = fsec;                        // 4096
    float* csA  = S + B_ROWS;                  // 512*16
    float* csP  = csA + D_DIM * CS_STRIDE;     // 512*16
    float* csN  = csP + D_DIM * CS_STRIDE;     // 512*16
    float* lsum = csN + D_DIM * CS_STRIDE;     // 1

    // ws is re-poisoned 0xAA before every launch -> zero all accumulators
    hipMemsetAsync(fsec, 0, (B_ROWS + 3 * D_DIM * CS_STRIDE + 1) * sizeof(float), stream);

    norm_colsum<<<1024, 256, 0, stream>>>(anc, pos, neg, a8, p8, n8, csA, csP, csN);

    gemm_epi<0><<<dim3(N_ROWS / BN, B_ROWS / BM), 512, 0, stream>>>(a8, n8, S, nullptr);
    gemm_epi<1><<<dim3(P_ROWS / BN, B_ROWS / BM), 512, 0, stream>>>(a8, p8, S, lsum);

    finalize_k<<<1, 512, 0, stream>>>(csA, csP, csN, lsum, out);
}

// Round 2
// 279.708 us; speedup vs baseline: 1.2024x; 1.2024x over previous
//
#include <hip/hip_runtime.h>
#include <hip/hip_bf16.h>

// InfoNCE: a[4096,512], p[4096,512], n[16384,512] f32 -> 4 f32 scalars.
// R6: revert to R4 GEMM structure (BK=128 tiles, 32KB LDS, multi-block/CU,
//     conflict-free b128 K-permuted reads) + XCD-aware tile swizzle (T1).
//     R5 post-mortem: whole-K 128KB LDS -> 1 block/CU serialized staging
//     (9.3 GB/s/CU) + stride-512 bank conflicts (+4cyc/read). Reverted.
//     R4 re-diagnosis: 512MB of L2/L3 gather traffic at only 4.65 TB/s --
//     default round-robin dispatch scatters an m-band's n-tiles across XCDs,
//     so each XCD's working set is all of n8 (8MB) > 4MB L2. Swizzle gives
//     each XCD a contiguous 16-n-tile chunk (1MB) swept over m -> L2-local.
// ws layout: a8(2MB) p8(2MB) n8(8MB) | S[4096] csA[512*16] csP[512*16] csN[512*16] lsum[1]

#define D_DIM 512
#define B_ROWS 4096
#define P_ROWS 4096
#define N_ROWS 16384
#define INV_T 14.285714285714286f
#define EPS_L 1e-8f
#define CS_STRIDE 16  // colsum accumulators spread 64B apart -> atomics hit distinct lines

typedef unsigned char fp8_t;
typedef __attribute__((ext_vector_type(4))) float floatx4;   // MFMA C/D frag
typedef __attribute__((ext_vector_type(2))) long longx2;     // 16B LDS read = 2 MFMA operands
typedef unsigned int uint32;

// ---- fused: L2-normalize rows -> fp8 e4m3, and accumulate fp32 column sums ----
// grid = 1024 blocks x 256 thr. Segments: b<256 -> A, b<512 -> P, else -> N.
__global__ __launch_bounds__(256) void norm_colsum(
        const float* __restrict__ a, const float* __restrict__ p, const float* __restrict__ n,
        fp8_t* __restrict__ a8, fp8_t* __restrict__ p8, fp8_t* __restrict__ n8,
        float* __restrict__ csA, float* __restrict__ csP, float* __restrict__ csN) {
    const float* in; fp8_t* outp; float* cs; int rows, nb, bseg;
    int b = blockIdx.x;
    if (b < 256)      { in = a; outp = a8; cs = csA; rows = B_ROWS; nb = 256; bseg = b; }
    else if (b < 512) { in = p; outp = p8; cs = csP; rows = P_ROWS; nb = 256; bseg = b - 256; }
    else              { in = n; outp = n8; cs = csN; rows = N_ROWS; nb = 512; bseg = b - 512; }

    const int wave = threadIdx.x >> 6;
    const int lane = threadIdx.x & 63;

    float cs0[4] = {0.f, 0.f, 0.f, 0.f};
    float cs1[4] = {0.f, 0.f, 0.f, 0.f};

    for (int chunk = bseg; chunk < (rows >> 2); chunk += nb) {
        int r = chunk * 4 + wave;
        const float4* rp = reinterpret_cast<const float4*>(in + (size_t)r * D_DIM);
        float4 v0 = rp[lane];
        float4 v1 = rp[lane + 64];
        float ss = v0.x*v0.x + v0.y*v0.y + v0.z*v0.z + v0.w*v0.w
                 + v1.x*v1.x + v1.y*v1.y + v1.z*v1.z + v1.w*v1.w;
#pragma unroll
        for (int off = 1; off < 64; off <<= 1) ss += __shfl_xor(ss, off);
        float inv = 1.0f / fmaxf(sqrtf(ss), 1e-12f);
        float f0x = v0.x*inv, f0y = v0.y*inv, f0z = v0.z*inv, f0w = v0.w*inv;
        float f1x = v1.x*inv, f1y = v1.y*inv, f1z = v1.z*inv, f1w = v1.w*inv;
        cs0[0] += f0x; cs0[1] += f0y; cs0[2] += f0z; cs0[3] += f0w;
        cs1[0] += f1x; cs1[1] += f1y; cs1[2] += f1z; cs1[3] += f1w;
        // pack 4 floats -> 4 fp8 e4m3 bytes (RNE hw cvt)
        int pk0 = __builtin_amdgcn_cvt_pk_fp8_f32(f0x, f0y, 0, 0);
        pk0     = __builtin_amdgcn_cvt_pk_fp8_f32(f0z, f0w, pk0, 1);
        int pk1 = __builtin_amdgcn_cvt_pk_fp8_f32(f1x, f1y, 0, 0);
        pk1     = __builtin_amdgcn_cvt_pk_fp8_f32(f1z, f1w, pk1, 1);
        uint32* op = reinterpret_cast<uint32*>(outp + (size_t)r * D_DIM);
        op[lane]      = (uint32)pk0;   // bytes 4*lane .. 4*lane+3
        op[lane + 64] = (uint32)pk1;   // bytes 256+4*lane ..
    }

    // block-level colsum reduce: LDS atomics (4-way max contention), then one
    // global atomic per column per block, spread across 64B lines.
    __shared__ float csh[D_DIM];
    if (threadIdx.x < 256) { csh[threadIdx.x] = 0.f; csh[threadIdx.x + 256] = 0.f; }
    __syncthreads();
#pragma unroll
    for (int j = 0; j < 4; ++j) {
        atomicAdd(&csh[lane * 4 + j], cs0[j]);
        atomicAdd(&csh[256 + lane * 4 + j], cs1[j]);
    }
    __syncthreads();
    if (threadIdx.x < 256) {
        atomicAdd(&cs[(size_t)threadIdx.x * CS_STRIDE], csh[threadIdx.x]);
        atomicAdd(&cs[(size_t)(threadIdx.x + 256) * CS_STRIDE], csh[threadIdx.x + 256]);
    }
}

// ---------------- fp8 MFMA GEMM with fused epilogue ----------------
#define BM 128
#define BN 128
#define BKB 128  // K-elements per tile == bytes per row per tile (fp8)

typedef const __attribute__((address_space(1))) unsigned int* as1_u32p;
typedef __attribute__((address_space(3))) unsigned int* as3_u32p;

__device__ __forceinline__ void load_lds16(const void* g, void* l) {
    // each lane writes 16B at (wave-uniform l) + lane*16
    __builtin_amdgcn_global_load_lds((as1_u32p)g, (as3_u32p)l, 16, 0, 0);
}

// EPI==0: C = A@Bm^T, S[row] += sum_col exp(C*invT)           (neg pass)
// EPI==1: loss_sum += sum(-log(exp(C*invT)/(exp+S[row])+eps)) (pos pass)
template <int EPI>
__global__ __launch_bounds__(256, 4) void gemm_epi(const fp8_t* __restrict__ A,
                                                   const fp8_t* __restrict__ Bm,
                                                   float* __restrict__ S,
                                                   float* __restrict__ loss_sum) {
    __shared__ fp8_t As[BM * BKB];  // 16 KB, swizzled 16B granules
    __shared__ fp8_t Bs[BN * BKB];  // 16 KB

    const int tid  = threadIdx.x;
    const int lane = tid & 63;
    const int w    = tid >> 6;          // wave 0..3
    const int wm   = w >> 1, wn = w & 1;

    // ---- XCD-aware tile swizzle (T1): hw dispatch round-robins linear wg id
    // across 8 XCDs. Give XCD x a contiguous chunk of GX/8 n-tiles, swept
    // with n fastest -> per-XCD L2 working set = chunk of B (1MB for gemm0)
    // + hot A-panel, instead of all of n8 (8MB > 4MB L2). nwg%8==0 always.
    const int GX  = gridDim.x;                       // n-tiles (128 or 32)
    const int bid = blockIdx.y * GX + blockIdx.x;    // x-fastest linear id
    const int xcd = bid & 7;
    const int idx = bid >> 3;                        // 0 .. nwg/8-1
    const int NX  = GX >> 3;                         // n-tiles per XCD
    const int bx  = xcd * NX + (idx % NX);
    const int by  = idx / NX;

    const int m0   = by * BM;
    const int n0   = bx * BN;
    const int lr   = lane & 15;         // row-in-16-tile for frags
    const int q    = lane >> 4;         // quad 0..3

    floatx4 acc[4][4];
#pragma unroll
    for (int i = 0; i < 4; ++i)
#pragma unroll
        for (int j = 0; j < 4; ++j) acc[i][j] = (floatx4){0.f, 0.f, 0.f, 0.f};

    // staging: lane fetches row (rbase + lane>>3), 16B granule (lane&7)^(lane>>3)
    // (XOR swizzle folded into gather; global_load_lds LDS dest is lane-contiguous)
    const int srow   = lane >> 3;            // 0..7
    const int schunk = (lane & 7) ^ srow;    // swizzled 16B granule index 0..7

    for (int kt = 0; kt < D_DIM; kt += BKB) {
        __syncthreads();  // prior ds_reads done before overwrite
#pragma unroll
        for (int i = 0; i < 4; ++i) {
            int rbase = w * 32 + i * 8;  // 8-aligned -> (row&7)==(lane>>3)
            const fp8_t* asrc = A + (size_t)(m0 + rbase + srow) * D_DIM + kt + schunk * 16;
            load_lds16(asrc, &As[rbase * BKB]);
            const fp8_t* bsrc = Bm + (size_t)(n0 + rbase + srow) * D_DIM + kt + schunk * 16;
            load_lds16(bsrc, &Bs[rbase * BKB]);
        }
        __syncthreads();  // staging drained (compiler emits vmcnt(0) before barrier)

        // K-permuted fragment reads: lane reads granule g = t*4+q (b128,
        // conflict-free phase pattern), halves feed MFMA calls 2t and 2t+1.
        // Same (t,q,h)->k mapping for A and B => dot product is exact.
#pragma unroll
        for (int t = 0; t < 2; ++t) {
            longx2 af[4], bfr[4];
            const int g = t * 4 + q;
#pragma unroll
            for (int rt = 0; rt < 4; ++rt) {
                int r = wm * 64 + rt * 16 + lr;
                int off = (g ^ (r & 7)) << 4;
                af[rt] = *reinterpret_cast<const longx2*>(&As[r * BKB + off]);
            }
#pragma unroll
            for (int ct = 0; ct < 4; ++ct) {
                int r = wn * 64 + ct * 16 + lr;
                int off = (g ^ (r & 7)) << 4;
                bfr[ct] = *reinterpret_cast<const longx2*>(&Bs[r * BKB + off]);
            }
#pragma unroll
            for (int rt = 0; rt < 4; ++rt)
#pragma unroll
                for (int ct = 0; ct < 4; ++ct)
                    acc[rt][ct] = __builtin_amdgcn_mfma_f32_16x16x32_fp8_fp8(af[rt].x, bfr[ct].x,
                                                                             acc[rt][ct], 0, 0, 0);
#pragma unroll
            for (int rt = 0; rt < 4; ++rt)
#pragma unroll
                for (int ct = 0; ct < 4; ++ct)
                    acc[rt][ct] = __builtin_amdgcn_mfma_f32_16x16x32_fp8_fp8(af[rt].y, bfr[ct].y,
                                                                             acc[rt][ct], 0, 0, 0);
        }
    }

    // C/D layout: col = lane&15, row = (lane>>4)*4 + reg
    if (EPI == 0) {
#pragma unroll
        for (int rt = 0; rt < 4; ++rt) {
#pragma unroll
            for (int reg = 0; reg < 4; ++reg) {
                float v = 0.f;
#pragma unroll
                for (int ct = 0; ct < 4; ++ct) v += __expf(acc[rt][ct][reg] * INV_T);
                v += __shfl_xor(v, 1);
                v += __shfl_xor(v, 2);
                v += __shfl_xor(v, 4);
                v += __shfl_xor(v, 8);
                if (lr == 0) {
                    int row = m0 + wm * 64 + rt * 16 + q * 4 + reg;
                    atomicAdd(&S[row], v);
                }
            }
        }
    } else {
        float lsum = 0.f;
#pragma unroll
        for (int rt = 0; rt < 4; ++rt) {
#pragma unroll
            for (int reg = 0; reg < 4; ++reg) {
                int row = m0 + wm * 64 + rt * 16 + q * 4 + reg;
                float Sv = S[row];
#pragma unroll
                for (int ct = 0; ct < 4; ++ct) {
                    float pe = __expf(acc[rt][ct][reg] * INV_T);
                    lsum -= __logf(pe / (pe + Sv) + EPS_L);
                }
            }
        }
#pragma unroll
        for (int off = 1; off < 64; off <<= 1) lsum += __shfl_xor(lsum, off);
        if (lane == 0) atomicAdd(loss_sum, lsum);
    }
}

// ---- finalize: dot the (strided) column sums, emit the 4 scalars ----
__global__ void finalize_k(const float* __restrict__ csA, const float* __restrict__ csP,
                           const float* __restrict__ csN, const float* __restrict__ lsum,
                           float* __restrict__ out) {
    int tid = threadIdx.x;  // 512
    float av = csA[(size_t)tid * CS_STRIDE];
    float dp = av * csP[(size_t)tid * CS_STRIDE];
    float dn = av * csN[(size_t)tid * CS_STRIDE];
#pragma unroll
    for (int off = 1; off < 64; off <<= 1) {
        dp += __shfl_xor(dp, off);
        dn += __shfl_xor(dn, off);
    }
    __shared__ float red[16];
    int wid = tid >> 6, lane = tid & 63;
    if (lane == 0) { red[wid] = dp; red[8 + wid] = dn; }
    __syncthreads();
    if (tid == 0) {
        float sdp = 0.f, sdn = 0.f;
#pragma unroll
        for (int i = 0; i < 8; ++i) { sdp += red[i]; sdn += red[8 + i]; }
        float mean_pos = sdp * INV_T / ((float)B_ROWS * (float)P_ROWS);
        float mean_neg = sdn * INV_T / ((float)B_ROWS * (float)N_ROWS);
        out[0] = lsum[0] / ((float)B_ROWS * (float)P_ROWS);
        out[1] = mean_pos;
        out[2] = mean_neg;
        out[3] = mean_pos - mean_neg;
    }
}

extern "C" void kernel_launch(void* const* d_in, const int* in_sizes, int n_in,
                              void* d_out, int out_size, void* d_ws, size_t ws_size,
                              hipStream_t stream) {
    const float* anc = (const float*)d_in[0];
    const float* pos = (const float*)d_in[1];
    const float* neg = (const float*)d_in[2];
    float* out = (float*)d_out;

    fp8_t* a8 = (fp8_t*)d_ws;
    fp8_t* p8 = a8 + (size_t)B_ROWS * D_DIM;
    fp8_t* n8 = p8 + (size_t)P_ROWS * D_DIM;
    float* fsec = (float*)(n8 + (size_t)N_ROWS * D_DIM);  // 12MB offset, 64B-aligned
    float* S    = fsec;                        // 4096
    float* csA  = S + B_ROWS;                  // 512*16
    float* csP  = csA + D_DIM * CS_STRIDE;     // 512*16
    float* csN  = csP + D_DIM * CS_STRIDE;     // 512*16
    float* lsum = csN + D_DIM * CS_STRIDE;     // 1

    // ws is re-poisoned 0xAA before every launch -> zero all accumulators
    hipMemsetAsync(fsec, 0, (B_ROWS + 3 * D_DIM * CS_STRIDE + 1) * sizeof(float), stream);

    norm_colsum<<<1024, 256, 0, stream>>>(anc, pos, neg, a8, p8, n8, csA, csP, csN);

    gemm_epi<0><<<dim3(N_ROWS / BN, B_ROWS / BM), 256, 0, stream>>>(a8, n8, S, nullptr);
    gemm_epi<1><<<dim3(P_ROWS / BN, B_ROWS / BM), 256, 0, stream>>>(a8, p8, S, lsum);

    finalize_k<<<1, 512, 0, stream>>>(csA, csP, csN, lsum, out);
}